// Round 9
// baseline (174.962 us; speedup 1.0000x reference)
//
#include <hip/hip_runtime.h>

// DenseCRF-RNN fwd, D=64,H=128,W=128, L=2, 5 iters (6 launches, no coop —
// R7 showed hipLaunchCooperativeKernel errors on this platform).
// q1 = sigmoid(cur1-cur0); delta = P - Ac*blur3d(q) - M*num(q);
// num = sum_27 w255_o(x)*q(x+d_o), u8 weights (tile-blocked, coalesced).
// R9: q lives in a GUARD-PADDED volume 68x132x136 (halo z2/y2/x4, offset 36180)
//   -> iter staging is 864 unconditional aligned float4 loads (was 2880 scalar
//   conditional), all LDS reads aligned b128. Borders zeroed in pre prologue
//   (disjoint from interior writes), stay zero: iters write interior only.
// ws: qA | qB (padded, 4.9 MB ea) | P | M (flat NN) | W u8 28.3 MB  (~47 MB).

#define DD 64
#define HH 128
#define WW 128
#define NN (DD*HH*WW)     // 1048576
#define PAD 264
#define TILE_WU 6912      // u32 per tile weight block: 27 * 256
#define XP 136            // padded x pitch (x in [-4,131])
#define SLICE (132*136)   // 17952: padded y pitch 132 (y in [-2,129])
#define QTOT (68*SLICE)   // 1220736: z in [-2,65]
#define QOFF (2*SLICE + 2*XP + 4)   // 36180, %4==0

__device__ __forceinline__ float bfac(int p, int dim) {
    const float K[5] = {0.05448868f, 0.24420134f, 0.40261995f, 0.24420134f, 0.05448868f};
    float s = 0.f;
#pragma unroll
    for (int o = -2; o <= 2; ++o) {
        int pp = p + o;
        s += (pp >= 0 && pp < dim) ? K[o + 2] : 0.f;
    }
    return s;
}

__device__ __forceinline__ void ldrow(const float* p, float* r) {
    float4 a = *(const float4*)p;
    float4 b = *(const float4*)(p + 4);
    r[0] = a.x; r[1] = a.y; r[2] = a.z; r[3] = a.w;
    r[4] = b.x; r[5] = b.y; r[6] = b.z; r[7] = b.w;
}

// Tile 8z x 8y x 16x, 256 threads, 4 x-voxels/thread (same geometry as iter).
__global__ __launch_bounds__(256, 4) void crf_pre(
    const float* __restrict__ img, const float* __restrict__ h,
    const float* __restrict__ f1, const float* __restrict__ w0,
    const float* __restrict__ sw, const float* __restrict__ bw,
    const float* __restrict__ cm,
    float* __restrict__ qA, float* __restrict__ qB,
    float* __restrict__ P, float* __restrict__ M,
    unsigned int* __restrict__ W, float* __restrict__ out)
{
    const float Sc[4] = {1.f, 0.80073740f, 0.64118039f, 0.51341712f};
    __shared__ float ims[10][10][20];

    const int tid = threadIdx.x;
    const int x0 = blockIdx.x * 16, y0 = blockIdx.y * 8, z0 = blockIdx.z * 8;
    const int T = ((int)blockIdx.z * 16 + (int)blockIdx.y) * 8 + (int)blockIdx.x;

    // ---- zero the q guard borders (disjoint from interior writes below) ----
    {
        int gtid = T * 256 + tid;
        for (int lin = gtid; lin < QTOT; lin += 262144) {
            int zq = lin / SLICE, r = lin - zq * SLICE;
            int yq = r / XP, xq = r - yq * XP;
            bool inter = (zq >= 2 && zq < 66 && yq >= 2 && yq < 130 &&
                          xq >= 4 && xq < 132);
            if (!inter) { qA[lin] = 0.f; qB[lin] = 0.f; }
        }
    }

    float* imf = &ims[0][0][0];
    for (int idx = tid; idx < 2000; idx += 256) {
        int lz2 = idx / 200, r = idx - lz2 * 200, ly2 = r / 20, lx2 = r - ly2 * 20;
        int gz = z0 + lz2 - 1, gy = y0 + ly2 - 1, gx = x0 + lx2 - 1;
        float v = 0.f;
        if ((unsigned)gz < 64u && (unsigned)gy < 128u && (unsigned)gx < 128u)
            v = img[(gz << 14) + (gy << 7) + gx];
        imf[idx] = v;
    }
    __syncthreads();

    const int lx = (tid & 3) * 4, ly = (tid >> 2) & 7, lz = tid >> 5;
    const int x = x0 + lx, y = y0 + ly, z = z0 + lz;
    const int g = (z << 14) + (y << 7) + x;

    const float cd0 = cm[2] - cm[0], cd1 = cm[3] - cm[1];
    const float Ksp = cd0 * sw[0] + cd1 * sw[2];
    const float Kbl = cd0 * bw[0] + cd1 * bw[2];
    const float Bc  = cd0 * (bw[1] - bw[0]) + cd1 * (bw[3] - bw[2]);

    float rowC[8];
    ldrow(&ims[lz + 1][ly + 1][lx], rowC);
    const float Ic[4] = {rowC[1], rowC[2], rowC[3], rowC[4]};
    float den[4] = {0.f, 0.f, 0.f, 0.f}, numi[4] = {0.f, 0.f, 0.f, 0.f};
    unsigned int* __restrict__ Wt = W + T * TILE_WU;
    float rI[8];
#pragma unroll
    for (int r9 = 0; r9 < 9; ++r9) {
        const int dz = r9 / 3 - 1, dy = r9 % 3 - 1;
        ldrow(&ims[lz + 1 + dz][ly + 1 + dy][lx], rI);
        const bool zyin = ((unsigned)(z + dz) < 64u) && ((unsigned)(y + dy) < 128u);
#pragma unroll
        for (int c = 0; c < 3; ++c) {
            const int dx = c - 1;
            const float s = Sc[dz * dz + dy * dy + dx * dx];
            unsigned pack = 0;
#pragma unroll
            for (int xi = 0; xi < 4; ++xi) {
                float dd = Ic[xi] - rI[xi + c];
                float w = s * __expf(-2.f * dd * dd);
                den[xi] += w;
                bool inb = zyin && ((unsigned)(x + xi + dx) < 128u);
                numi[xi] += inb ? w : 0.f;
                pack |= ((unsigned)(w * 255.f + 0.5f)) << (8 * xi);
            }
            Wt[(r9 * 3 + c) * 256 + tid] = pack;   // 256-B/wave contiguous
        }
    }

    float4 h0v = *(const float4*)&h[g];
    float4 h1v = *(const float4*)&h[NN + g];
    float4 f1v = *(const float4*)&f1[g];
    float hh0[4] = {h0v.x, h0v.y, h0v.z, h0v.w};
    float hh1[4] = {h1v.x, h1v.y, h1v.z, h1v.w};
    float ff[4]  = {f1v.x, f1v.y, f1v.z, f1v.w};
    const float w00 = w0[0];
    const float bz = bfac(z, 64), by = bfac(y, 128);
    float qv[4], Pv[4], Mv[4];
#pragma unroll
    for (int xi = 0; xi < 4; ++xi) {
        float dq = hh1[xi] - hh0[xi];
        float logp = -0.5f * Ic[xi] * Ic[xi] - 0.91893853320467274f;
        float t = -(w00 + logp - ff[xi]);
        float bones = bz * by * bfac(x + xi, 128);
        qv[xi] = 1.f / (1.f + __expf(-dq));
        Pv[xi] = dq * t - Ksp * bones - Kbl * (numi[xi] / den[xi]);
        Mv[xi] = Bc / (den[xi] * 255.f);
    }
    *(float4*)&qA[z * SLICE + y * XP + x + QOFF] = {qv[0], qv[1], qv[2], qv[3]};
    *(float4*)&P[g] = {Pv[0], Pv[1], Pv[2], Pv[3]};
    *(float4*)&M[g] = {Mv[0], Mv[1], Mv[2], Mv[3]};
    *(float4*)&out[2 * NN + g] = f1v;   // f_1 passthrough
}

// Tile: 8z x 8y x 16x outputs, 256 threads, 4 x-voxels/thread.
template <bool LAST>
__global__ __launch_bounds__(256, 4) void crf_iter(
    const float* __restrict__ qsrc, float* __restrict__ qdst,
    const float* __restrict__ P, const float* __restrict__ M,
    const unsigned int* __restrict__ W,
    const float* __restrict__ sw, const float* __restrict__ cm,
    float* __restrict__ out)
{
    const float K0 = 0.05448868f, K1 = 0.24420134f, K2 = 0.40261995f;

    __shared__ float qs[12][12][24];   // q tile: z/y halo 2, x halo 4 (13.8 KB)
    __shared__ float t1[12][12][16];   // blur-x
    __shared__ float t2[12][8][16];    // blur-xy

    const int tid = threadIdx.x;
    const int x0 = blockIdx.x * 16, y0 = blockIdx.y * 8, zB = blockIdx.z * 8;
    const int T = ((int)blockIdx.z * 16 + (int)blockIdx.y) * 8 + (int)blockIdx.x;
    const int lx = (tid & 3) * 4, ly = (tid >> 2) & 7, lz = tid >> 5;
    const int g = ((zB + lz) << 14) + ((y0 + ly) << 7) + (x0 + lx);

    const float cd0 = cm[2] - cm[0], cd1 = cm[3] - cm[1];
    const float Ac = cd0 * (sw[1] - sw[0]) + cd1 * (sw[3] - sw[2]);

    // early prefetch: W/P/M -> registers (latency hides under staging/blur)
    const unsigned int* __restrict__ Wt = W + T * TILE_WU;
    unsigned w27[27];
#pragma unroll
    for (int o = 0; o < 27; ++o) w27[o] = Wt[o * 256 + tid];
    float4 Pv = *(const float4*)&P[g];
    float4 Mv = *(const float4*)&M[g];

    // stage q tile: 864 unconditional aligned float4 loads (guard-padded src)
    {
        const int zb = (zB - 2) * SLICE + (y0 - 2) * XP + (x0 - 4) + QOFF;
#pragma unroll
        for (int pass = 0; pass < 4; ++pass) {
            int i = pass * 256 + tid;
            if (i < 864) {
                int lz2 = i / 72, r = i - lz2 * 72;
                int ly2 = r / 6, lxf = r - ly2 * 6;
                float4 v = *(const float4*)&qsrc[zb + lz2 * SLICE + ly2 * XP + lxf * 4];
                *(float4*)&qs[lz2][ly2][lxf * 4] = v;
            }
        }
    }
    __syncthreads();

    // blur along x (aligned b128 triplets)
    for (int idx = tid; idx < 576; idx += 256) {
        int lz2 = idx / 48, r = idx - lz2 * 48, ly2 = r / 4, c4 = (r - ly2 * 4) * 4;
        const float* rp = &qs[lz2][ly2][0];
        float4 A = *(const float4*)&rp[c4];
        float4 B = *(const float4*)&rp[c4 + 4];
        float4 C = *(const float4*)&rp[c4 + 8];
        float4 o;
        o.x = K0 * (A.z + B.z) + K1 * (A.w + B.y) + K2 * B.x;
        o.y = K0 * (A.w + B.w) + K1 * (B.x + B.z) + K2 * B.y;
        o.z = K0 * (B.x + C.x) + K1 * (B.y + B.w) + K2 * B.z;
        o.w = K0 * (B.y + C.y) + K1 * (B.z + C.x) + K2 * B.w;
        *(float4*)&t1[lz2][ly2][c4] = o;
    }
    __syncthreads();

    // blur along y
    for (int idx = tid; idx < 384; idx += 256) {
        int lz2 = idx / 32, r = idx - lz2 * 32, ly2 = r / 4, c4 = (r - ly2 * 4) * 4;
        float4 r0 = *(const float4*)&t1[lz2][ly2][c4];
        float4 r1 = *(const float4*)&t1[lz2][ly2 + 1][c4];
        float4 r2 = *(const float4*)&t1[lz2][ly2 + 2][c4];
        float4 r3 = *(const float4*)&t1[lz2][ly2 + 3][c4];
        float4 r4 = *(const float4*)&t1[lz2][ly2 + 4][c4];
        float4 o;
        o.x = K0 * (r0.x + r4.x) + K1 * (r1.x + r3.x) + K2 * r2.x;
        o.y = K0 * (r0.y + r4.y) + K1 * (r1.y + r3.y) + K2 * r2.y;
        o.z = K0 * (r0.z + r4.z) + K1 * (r1.z + r3.z) + K2 * r2.z;
        o.w = K0 * (r0.w + r4.w) + K1 * (r1.w + r3.w) + K2 * r2.w;
        *(float4*)&t2[lz2][ly2][c4] = o;
    }
    __syncthreads();

    // blur along z
    float4 za = *(const float4*)&t2[lz][ly][lx];
    float4 zb4 = *(const float4*)&t2[lz + 1][ly][lx];
    float4 zc = *(const float4*)&t2[lz + 2][ly][lx];
    float4 zd = *(const float4*)&t2[lz + 3][ly][lx];
    float4 ze = *(const float4*)&t2[lz + 4][ly][lx];
    float sp[4];
    sp[0] = K0 * (za.x + ze.x) + K1 * (zb4.x + zd.x) + K2 * zc.x;
    sp[1] = K0 * (za.y + ze.y) + K1 * (zb4.y + zd.y) + K2 * zc.y;
    sp[2] = K0 * (za.z + ze.z) + K1 * (zb4.z + zd.z) + K2 * zc.z;
    sp[3] = K0 * (za.w + ze.w) + K1 * (zb4.w + zd.w) + K2 * zc.w;

    // bilateral: 27 dirs, u8 weights from registers, aligned b128 row reads
    float num[4] = {0.f, 0.f, 0.f, 0.f};
    float qrow[12];
#pragma unroll
    for (int r9 = 0; r9 < 9; ++r9) {
        const int dz = r9 / 3 - 1, dy = r9 % 3 - 1;
        const float* rp2 = &qs[lz + 2 + dz][ly + 2 + dy][0];
        float4 A = *(const float4*)&rp2[lx];
        float4 B = *(const float4*)&rp2[lx + 4];
        float4 C = *(const float4*)&rp2[lx + 8];
        qrow[0] = A.x; qrow[1] = A.y; qrow[2] = A.z; qrow[3] = A.w;
        qrow[4] = B.x; qrow[5] = B.y; qrow[6] = B.z; qrow[7] = B.w;
        qrow[8] = C.x; qrow[9] = C.y; qrow[10] = C.z; qrow[11] = C.w;
#pragma unroll
        for (int c = 0; c < 3; ++c) {
            unsigned wv = w27[r9 * 3 + c];
#pragma unroll
            for (int xi = 0; xi < 4; ++xi)
                num[xi] += (float)((wv >> (8 * xi)) & 0xffu) * qrow[3 + xi + c];
        }
    }

    float pr4[4] = {Pv.x, Pv.y, Pv.z, Pv.w};
    float mv4[4] = {Mv.x, Mv.y, Mv.z, Mv.w};
    float qn[4];
#pragma unroll
    for (int xi = 0; xi < 4; ++xi) {
        float dn = pr4[xi] - Ac * sp[xi] - mv4[xi] * num[xi];
        qn[xi] = 1.f / (1.f + __expf(-dn));
    }

    if (!LAST) {
        const int ql = (zB + lz) * SLICE + (y0 + ly) * XP + (x0 + lx) + QOFF;
        *(float4*)&qdst[ql] = {qn[0], qn[1], qn[2], qn[3]};
    } else {
        float4 o1 = {qn[0], qn[1], qn[2], qn[3]};
        float4 o0 = {1.f - qn[0], 1.f - qn[1], 1.f - qn[2], 1.f - qn[3]};
        *(float4*)&out[g] = o0;
        *(float4*)&out[NN + g] = o1;
    }
}

extern "C" void kernel_launch(void* const* d_in, const int* in_sizes, int n_in,
                              void* d_out, int out_size, void* d_ws, size_t ws_size,
                              hipStream_t stream)
{
    const float* img = (const float*)d_in[0];
    const float* h   = (const float*)d_in[1];
    const float* f1  = (const float*)d_in[2];
    const float* w0  = (const float*)d_in[3];
    const float* sw  = (const float*)d_in[4];
    const float* bw  = (const float*)d_in[5];
    const float* cm  = (const float*)d_in[6];
    float* out = (float*)d_out;

    float* qA = (float*)d_ws;
    float* qB = qA + (QTOT + PAD);
    float* P  = qB + (QTOT + PAD);
    float* M  = P + (NN + PAD);
    unsigned int* W = (unsigned int*)(M + (NN + PAD));

    dim3 grid(WW / 16, HH / 8, DD / 8);   // 1024 blocks
    crf_pre<<<grid, 256, 0, stream>>>(img, h, f1, w0, sw, bw, cm, qA, qB, P, M, W, out);
    crf_iter<false><<<grid, 256, 0, stream>>>(qA, qB, P, M, W, sw, cm, nullptr);
    crf_iter<false><<<grid, 256, 0, stream>>>(qB, qA, P, M, W, sw, cm, nullptr);
    crf_iter<false><<<grid, 256, 0, stream>>>(qA, qB, P, M, W, sw, cm, nullptr);
    crf_iter<false><<<grid, 256, 0, stream>>>(qB, qA, P, M, W, sw, cm, nullptr);
    crf_iter<true ><<<grid, 256, 0, stream>>>(qA, nullptr, P, M, W, sw, cm, out);
}